// Round 2
// baseline (276.572 us; speedup 1.0000x reference)
//
#include <hip/hip_runtime.h>
#include <hip/hip_bf16.h>
#include <math.h>

// MHA block: B=2, L=S=2048, D=768, H=12, hd=64. f32 in/out, bf16 MFMA inside.
// ws layout: Qp | Kp | Vt | Oatt (bf16, 6.29MB each) = 25.2MB.
// Pre-LN x (f32) lives in d_out; ln_kernel normalizes in place.

typedef unsigned short u16;
typedef unsigned int   u32;
typedef __bf16 bf16x8 __attribute__((ext_vector_type(8)));
typedef float  f32x4  __attribute__((ext_vector_type(4)));

#define DM   768
#define NH   12
#define HD   64
#define BB   2
#define SL   2048
#define MR   (BB*SL)   // 4096 rows

__device__ inline u16 f2bf(float f) {
    union { float f; u32 u; } v; v.f = f;
    u32 u = v.u;
    u += 0x7fffu + ((u >> 16) & 1u);   // RNE
    return (u16)(u >> 16);
}

// 8 contiguous f32 -> 8 bf16 packed in a uint4 (two float4 loads, RNE cvt)
__device__ inline uint4 cvt8(const float* src) {
    const float4* p = reinterpret_cast<const float4*>(src);
    float4 a = p[0], b = p[1];
    union { u16 h[8]; uint4 v; } u;
    u.h[0] = f2bf(a.x); u.h[1] = f2bf(a.y); u.h[2] = f2bf(a.z); u.h[3] = f2bf(a.w);
    u.h[4] = f2bf(b.x); u.h[5] = f2bf(b.y); u.h[6] = f2bf(b.z); u.h[7] = f2bf(b.w);
    return u.v;
}

// ---------------------------------------------------------------------------
// QKV projection: C[m][n] = sum_k X[m][k] * W[n][k]  (X: 4096x768 f32, W: 768x768 f32)
// 64x64 tile per block (4 waves, each 32x32 via 2x2 mfma_f32_16x16x32_bf16).
// mode 0/1: Q/K head-split  out[((b*12+h)*2048+l)*64+d]   (bf16)
// mode 2:   V transposed    out[((b*12+h)*64+d)*2048+l]   (bf16)
// ---------------------------------------------------------------------------
__global__ __launch_bounds__(256) void gemm_qkv(
    const float* __restrict__ xq, const float* __restrict__ xk, const float* __restrict__ xv,
    const float* __restrict__ wq, const float* __restrict__ wk, const float* __restrict__ wv,
    u16* __restrict__ oq, u16* __restrict__ ok, u16* __restrict__ ov)
{
    const int mode = blockIdx.z;
    const float* X = (mode == 0) ? xq : (mode == 1) ? xk : xv;
    const float* W = (mode == 0) ? wq : (mode == 1) ? wk : wv;
    u16* out       = (mode == 0) ? oq : (mode == 1) ? ok : ov;

    __shared__ __attribute__((aligned(16))) u16 As[64][72];
    __shared__ __attribute__((aligned(16))) u16 Ws[64][72];

    const int tid  = threadIdx.x;
    const int lane = tid & 63;
    const int w    = tid >> 6;
    const int wm   = (w >> 1) * 32;
    const int wn   = (w & 1) * 32;
    const int quad = lane >> 4;
    const int l16  = lane & 15;
    const int tm   = blockIdx.x * 64;
    const int tn   = blockIdx.y * 64;

    f32x4 acc[2][2] = {};

    for (int k0 = 0; k0 < 768; k0 += 64) {
        __syncthreads();
        #pragma unroll
        for (int rep = 0; rep < 2; rep++) {
            int idx = tid + rep * 256;          // 0..511
            int row = idx >> 3;                 // 0..63
            int col = (idx & 7) * 8;            // 0..56
            *reinterpret_cast<uint4*>(&As[row][col]) = cvt8(&X[(tm + row) * 768 + k0 + col]);
            *reinterpret_cast<uint4*>(&Ws[row][col]) = cvt8(&W[(tn + row) * 768 + k0 + col]);
        }
        __syncthreads();
        #pragma unroll
        for (int kk = 0; kk < 2; kk++) {
            bf16x8 a0 = *reinterpret_cast<const bf16x8*>(&As[wm + l16     ][kk*32 + quad*8]);
            bf16x8 a1 = *reinterpret_cast<const bf16x8*>(&As[wm + 16 + l16][kk*32 + quad*8]);
            bf16x8 b0 = *reinterpret_cast<const bf16x8*>(&Ws[wn + l16     ][kk*32 + quad*8]);
            bf16x8 b1 = *reinterpret_cast<const bf16x8*>(&Ws[wn + 16 + l16][kk*32 + quad*8]);
            acc[0][0] = __builtin_amdgcn_mfma_f32_16x16x32_bf16(a0, b0, acc[0][0], 0, 0, 0);
            acc[0][1] = __builtin_amdgcn_mfma_f32_16x16x32_bf16(a0, b1, acc[0][1], 0, 0, 0);
            acc[1][0] = __builtin_amdgcn_mfma_f32_16x16x32_bf16(a1, b0, acc[1][0], 0, 0, 0);
            acc[1][1] = __builtin_amdgcn_mfma_f32_16x16x32_bf16(a1, b1, acc[1][1], 0, 0, 0);
        }
    }

    #pragma unroll
    for (int i = 0; i < 2; i++)
        #pragma unroll
        for (int j = 0; j < 2; j++)
            #pragma unroll
            for (int r = 0; r < 4; r++) {
                int gm = tm + wm + i * 16 + quad * 4 + r;   // row (b*2048+l)
                int gn = tn + wn + j * 16 + l16;            // col (h*64+d)
                int b = gm >> 11, l = gm & 2047;
                int h = gn >> 6,  d = gn & 63;
                u16 bv = f2bf(acc[i][j][r]);
                if (mode == 2)
                    out[((b * 12 + h) * 64 + d) * 2048 + l] = bv;
                else
                    out[((b * 12 + h) * 2048 + l) * 64 + d] = bv;
            }
}

// out-proj: x[m][n] = Oatt[m]·W[n] + bias[n] + q[m][n]   (f32 out -> d_out)
__global__ __launch_bounds__(256) void gemm_out(
    const u16* __restrict__ Oa, const float* __restrict__ W,
    const float* __restrict__ bias, const float* __restrict__ resid,
    float* __restrict__ Xb)
{
    __shared__ __attribute__((aligned(16))) u16 As[64][72];
    __shared__ __attribute__((aligned(16))) u16 Ws[64][72];

    const int tid  = threadIdx.x;
    const int lane = tid & 63;
    const int w    = tid >> 6;
    const int wm   = (w >> 1) * 32;
    const int wn   = (w & 1) * 32;
    const int quad = lane >> 4;
    const int l16  = lane & 15;
    const int tm   = blockIdx.x * 64;
    const int tn   = blockIdx.y * 64;

    f32x4 acc[2][2] = {};

    for (int k0 = 0; k0 < 768; k0 += 64) {
        __syncthreads();
        #pragma unroll
        for (int rep = 0; rep < 2; rep++) {
            int idx = tid + rep * 256;
            int row = idx >> 3;
            int col = (idx & 7) * 8;
            *reinterpret_cast<uint4*>(&As[row][col]) =
                *reinterpret_cast<const uint4*>(&Oa[(tm + row) * 768 + k0 + col]);
            *reinterpret_cast<uint4*>(&Ws[row][col]) = cvt8(&W[(tn + row) * 768 + k0 + col]);
        }
        __syncthreads();
        #pragma unroll
        for (int kk = 0; kk < 2; kk++) {
            bf16x8 a0 = *reinterpret_cast<const bf16x8*>(&As[wm + l16     ][kk*32 + quad*8]);
            bf16x8 a1 = *reinterpret_cast<const bf16x8*>(&As[wm + 16 + l16][kk*32 + quad*8]);
            bf16x8 b0 = *reinterpret_cast<const bf16x8*>(&Ws[wn + l16     ][kk*32 + quad*8]);
            bf16x8 b1 = *reinterpret_cast<const bf16x8*>(&Ws[wn + 16 + l16][kk*32 + quad*8]);
            acc[0][0] = __builtin_amdgcn_mfma_f32_16x16x32_bf16(a0, b0, acc[0][0], 0, 0, 0);
            acc[0][1] = __builtin_amdgcn_mfma_f32_16x16x32_bf16(a0, b1, acc[0][1], 0, 0, 0);
            acc[1][0] = __builtin_amdgcn_mfma_f32_16x16x32_bf16(a1, b0, acc[1][0], 0, 0, 0);
            acc[1][1] = __builtin_amdgcn_mfma_f32_16x16x32_bf16(a1, b1, acc[1][1], 0, 0, 0);
        }
    }

    #pragma unroll
    for (int i = 0; i < 2; i++)
        #pragma unroll
        for (int j = 0; j < 2; j++)
            #pragma unroll
            for (int r = 0; r < 4; r++) {
                int gm = tm + wm + i * 16 + quad * 4 + r;
                int gn = tn + wn + j * 16 + l16;
                Xb[(size_t)gm * 768 + gn] = acc[i][j][r] + bias[gn] + resid[(size_t)gm * 768 + gn];
            }
}

// ---------------------------------------------------------------------------
// Flash-style attention. Block = (q-tile of 64 rows, head, batch); 4 waves,
// each owns 16 q-rows. Iterate 32 key-tiles of 64 with online softmax.
// Q/K layout [b][h][s][d] bf16; V transposed [b][h][d][s] bf16.
// ---------------------------------------------------------------------------
__global__ __launch_bounds__(256) void attn(
    const u16* __restrict__ Qp, const u16* __restrict__ Kp, const u16* __restrict__ Vt,
    const int* __restrict__ amask, u16* __restrict__ Oatt)
{
    __shared__ __attribute__((aligned(16))) u16 Ks[64][72];
    __shared__ __attribute__((aligned(16))) u16 Vs[64][72];
    __shared__ __attribute__((aligned(16))) u16 Ps[4][16][72];
    __shared__ float maskS[64];

    const int tid  = threadIdx.x;
    const int lane = tid & 63;
    const int w    = tid >> 6;
    const int quad = lane >> 4;
    const int l16  = lane & 15;
    const int qt = blockIdx.x;     // 0..31
    const int h  = blockIdx.y;     // 0..11
    const int b  = blockIdx.z;     // 0..1

    const u16* Qbase = Qp + ((size_t)(b * 12 + h) * 2048 + qt * 64) * 64;
    const u16* Kbase = Kp + (size_t)(b * 12 + h) * 2048 * 64;
    const u16* Vbase = Vt + (size_t)(b * 12 + h) * 64 * 2048;

    // Q A-fragments (reused across all key tiles): rows w*16+l16, k = kk*32+quad*8
    bf16x8 qfrag[2];
    #pragma unroll
    for (int kk = 0; kk < 2; kk++)
        qfrag[kk] = *reinterpret_cast<const bf16x8*>(&Qbase[(w * 16 + l16) * 64 + kk * 32 + quad * 8]);

    f32x4 oacc[4] = {};
    float mst[4], lst[4];
    #pragma unroll
    for (int r = 0; r < 4; r++) { mst[r] = -INFINITY; lst[r] = 0.0f; }

    for (int st = 0; st < 32; st++) {
        __syncthreads();
        #pragma unroll
        for (int rep = 0; rep < 2; rep++) {
            int idx = tid + rep * 256;
            int row = idx >> 3;
            int col = (idx & 7) * 8;
            *reinterpret_cast<uint4*>(&Ks[row][col]) =
                *reinterpret_cast<const uint4*>(&Kbase[(st * 64 + row) * 64 + col]);
            *reinterpret_cast<uint4*>(&Vs[row][col]) =
                *reinterpret_cast<const uint4*>(&Vbase[row * 2048 + st * 64 + col]);
        }
        if (tid < 64)
            maskS[tid] = (1.0f - (float)amask[b * 2048 + st * 64 + tid]) * -1000000.0f;
        __syncthreads();

        // scores: 16 q-rows x 64 keys per wave
        f32x4 sc[4];
        #pragma unroll
        for (int ct = 0; ct < 4; ct++) {
            f32x4 s = {};
            #pragma unroll
            for (int kk = 0; kk < 2; kk++) {
                bf16x8 kf = *reinterpret_cast<const bf16x8*>(&Ks[ct * 16 + l16][kk * 32 + quad * 8]);
                s = __builtin_amdgcn_mfma_f32_16x16x32_bf16(qfrag[kk], kf, s, 0, 0, 0);
            }
            float madd = maskS[ct * 16 + l16];
            #pragma unroll
            for (int r = 0; r < 4; r++) s[r] = s[r] * 0.125f + madd;
            sc[ct] = s;
        }

        // row max + online-softmax rescale factor (per lane: q-row = quad*4+r)
        float alpha[4];
        #pragma unroll
        for (int r = 0; r < 4; r++) {
            float mx = fmaxf(fmaxf(sc[0][r], sc[1][r]), fmaxf(sc[2][r], sc[3][r]));
            #pragma unroll
            for (int off = 8; off >= 1; off >>= 1)
                mx = fmaxf(mx, __shfl_xor(mx, off, 64));
            float mnew = fmaxf(mst[r], mx);
            alpha[r] = __expf(mst[r] - mnew);
            mst[r] = mnew;
        }

        // p = exp(s - m), write to LDS (C-layout -> A-layout round trip), rowsum
        float psum[4] = {0.f, 0.f, 0.f, 0.f};
        #pragma unroll
        for (int ct = 0; ct < 4; ct++)
            #pragma unroll
            for (int r = 0; r < 4; r++) {
                float p = __expf(sc[ct][r] - mst[r]);
                psum[r] += p;
                Ps[w][quad * 4 + r][ct * 16 + l16] = f2bf(p);
            }
        #pragma unroll
        for (int r = 0; r < 4; r++) {
            float ps = psum[r];
            #pragma unroll
            for (int off = 8; off >= 1; off >>= 1)
                ps += __shfl_xor(ps, off, 64);
            lst[r] = lst[r] * alpha[r] + ps;
        }
        #pragma unroll
        for (int ct = 0; ct < 4; ct++)
            #pragma unroll
            for (int r = 0; r < 4; r++)
                oacc[ct][r] *= alpha[r];
        __syncthreads();

        // O += P·V  (P from LDS in A-layout; V^T tile gives contiguous B-frags)
        bf16x8 pf[2];
        #pragma unroll
        for (int kk = 0; kk < 2; kk++)
            pf[kk] = *reinterpret_cast<const bf16x8*>(&Ps[w][l16][kk * 32 + quad * 8]);
        #pragma unroll
        for (int ct = 0; ct < 4; ct++)
            #pragma unroll
            for (int kk = 0; kk < 2; kk++) {
                bf16x8 vf = *reinterpret_cast<const bf16x8*>(&Vs[ct * 16 + l16][kk * 32 + quad * 8]);
                oacc[ct] = __builtin_amdgcn_mfma_f32_16x16x32_bf16(pf[kk], vf, oacc[ct], 0, 0, 0);
            }
    }

    // normalize and write merged-head output (B*L, 768) bf16
    #pragma unroll
    for (int r = 0; r < 4; r++) lst[r] = 1.0f / lst[r];
    #pragma unroll
    for (int ct = 0; ct < 4; ct++)
        #pragma unroll
        for (int r = 0; r < 4; r++) {
            int grow = b * 2048 + qt * 64 + w * 16 + quad * 4 + r;
            int gcol = h * 64 + ct * 16 + l16;
            Oatt[(size_t)grow * 768 + gcol] = f2bf(oacc[ct][r] * lst[r]);
        }
}

// ---------------------------------------------------------------------------
// LayerNorm over D=768, one block per row, in place on d_out (f32).
// ---------------------------------------------------------------------------
__global__ __launch_bounds__(256) void ln_kernel(
    float* __restrict__ X, const float* __restrict__ gamma,
    const float* __restrict__ beta)
{
    const int row = blockIdx.x;
    const int tid = threadIdx.x;
    float* xr = X + (size_t)row * 768;

    float v[3], s = 0.f, s2 = 0.f;
    #pragma unroll
    for (int i = 0; i < 3; i++) {
        v[i] = xr[tid + i * 256];
        s += v[i];
        s2 += v[i] * v[i];
    }
    #pragma unroll
    for (int off = 32; off >= 1; off >>= 1) {
        s  += __shfl_xor(s,  off, 64);
        s2 += __shfl_xor(s2, off, 64);
    }
    __shared__ float rs[4], rs2[4];
    int w = tid >> 6, lane = tid & 63;
    if (lane == 0) { rs[w] = s; rs2[w] = s2; }
    __syncthreads();
    s  = rs[0] + rs[1] + rs[2] + rs[3];
    s2 = rs2[0] + rs2[1] + rs2[2] + rs2[3];
    float mu = s * (1.0f / 768.0f);
    float var = s2 * (1.0f / 768.0f) - mu * mu;
    float rstd = rsqrtf(var + 1e-5f);
    #pragma unroll
    for (int i = 0; i < 3; i++) {
        int c = tid + i * 256;
        xr[c] = (v[i] - mu) * rstd * gamma[c] + beta[c];
    }
}

extern "C" void kernel_launch(void* const* d_in, const int* in_sizes, int n_in,
                              void* d_out, int out_size, void* d_ws, size_t ws_size,
                              hipStream_t stream)
{
    const float* q   = (const float*)d_in[0];
    const float* k   = (const float*)d_in[1];
    const float* v   = (const float*)d_in[2];
    const int*   am  = (const int*)d_in[3];
    const float* Wq  = (const float*)d_in[4];
    const float* Wk  = (const float*)d_in[5];
    const float* Wv  = (const float*)d_in[6];
    const float* W   = (const float*)d_in[7];
    const float* bb  = (const float*)d_in[8];
    const float* gam = (const float*)d_in[9];
    const float* bet = (const float*)d_in[10];

    u16* Qp = (u16*)d_ws;
    u16* Kp = Qp + (size_t)MR * DM;
    u16* Vt = Kp + (size_t)MR * DM;
    u16* Oa = Vt + (size_t)MR * DM;
    float* Xb = (float*)d_out;   // pre-LN x lives in d_out; LN is in place

    gemm_qkv<<<dim3(64, 12, 3), 256, 0, stream>>>(q, k, v, Wq, Wk, Wv, Qp, Kp, Vt);
    attn<<<dim3(32, 12, 2), 256, 0, stream>>>(Qp, Kp, Vt, am, Oa);
    gemm_out<<<dim3(64, 12), 256, 0, stream>>>(Oa, W, bb, q, Xb);
    ln_kernel<<<4096, 256, 0, stream>>>(Xb, gam, bet);
}